// Round 14
// baseline (212.800 us; speedup 1.0000x reference)
//
#include <hip/hip_runtime.h>
#include <hip/hip_bf16.h>
#include <cstdint>

#define NEG 0.2f
#define SBS 256

typedef __attribute__((ext_vector_type(8))) short bf16x8;
typedef __attribute__((ext_vector_type(8))) unsigned short ushort8;
typedef __attribute__((ext_vector_type(4))) float f32x4;

__device__ __forceinline__ float bf2f(unsigned short u){
  return __uint_as_float(((unsigned)u)<<16);
}
__device__ __forceinline__ unsigned short f2bf(float f){
  __hip_bfloat16 b = __float2bfloat16(f);   // RNE
  return *reinterpret_cast<unsigned short*>(&b);
}

// ---- embed: w_att in LDS, thread-per-node h/a_s/a_d; zeroes deg + gcount ----
__global__ __launch_bounds__(256)
void embed_kernel(const float* __restrict__ x, const float* __restrict__ emb_w,
                  const float* __restrict__ emb_b, const float* __restrict__ gat_w,
                  const float* __restrict__ att_src, const float* __restrict__ att_dst,
                  unsigned short* __restrict__ h_bf, float* __restrict__ a_s,
                  float* __restrict__ a_d, int* __restrict__ deg,
                  int* __restrict__ gcount, int nN)
{
  __shared__ float watt[768];     // [0:384)=src (h*128+k), [384:768)=dst
  int tid = threadIdx.x;

  #pragma unroll
  for (int r=0;r<3;r++){
    int o = tid + r*256;          // 0..767
    int isD = (o >= 384);
    int t2 = isD ? (o-384) : o;
    int h = t2 >> 7, k = t2 & 127;
    const float* att = isD ? (att_dst + h*128) : (att_src + h*128);
    const float* gw  = gat_w + (size_t)k*384 + h*128;
    float dot = 0.f;
    #pragma unroll 8
    for (int c=0;c<128;c++) dot += gw[c]*att[c];
    watt[o] = dot;
  }
  __syncthreads();

  int n = blockIdx.x*256 + tid;
  if (n < nN) deg[n] = 0;
  if (blockIdx.x==0 && tid==0) gcount[0] = 0;
  if (n >= nN) return;

  float xv[9];
  #pragma unroll
  for (int k=0;k<9;k++) xv[k] = x[(size_t)n*9 + k];

  float s0=0.f,s1=0.f,s2=0.f, d0=0.f,d1=0.f,d2=0.f;
  unsigned short* hrow = h_bf + (size_t)n*128;

  #pragma unroll 4
  for (int c0=0; c0<128; c0+=8){
    unsigned short pk[8];
    #pragma unroll
    for (int j=0;j<8;j++){
      int c = c0 + j;
      float acc = emb_b[c];
      #pragma unroll
      for (int k=0;k<9;k++) acc += xv[k]*emb_w[k*128+c];
      pk[j] = f2bf(acc);
      s0 += acc*watt[c]; s1 += acc*watt[128+c]; s2 += acc*watt[256+c];
      d0 += acc*watt[384+c]; d1 += acc*watt[512+c]; d2 += acc*watt[640+c];
    }
    *(int4*)(hrow + c0) = *(int4*)pk;
  }
  a_s[(size_t)n*3+0]=s0; a_s[(size_t)n*3+1]=s1; a_s[(size_t)n*3+2]=s2;
  a_d[(size_t)n*3+0]=d0; a_d[(size_t)n*3+1]=d1; a_d[(size_t)n*3+2]=d2;
}

// ---- deg histogram (scattered atomics over 50K counters); extra blocks Bt2 ----
__global__ __launch_bounds__(256)
void deg_kernel(const int* __restrict__ ei, int* __restrict__ deg,
                const float* __restrict__ gat_w,
                unsigned short* __restrict__ Bt2, int nE, int ebN)
{
  if (blockIdx.x < (unsigned)ebN){
    int e = blockIdx.x*256 + threadIdx.x;
    if (e < nE) atomicAdd(&deg[ei[nE + e]], 1);
  } else {
    int i = (blockIdx.x - ebN)*256 + threadIdx.x;   // 0..49151
    if (i < 12*128*32){
      int ks  = i >> 12;
      int rem = i & 4095;
      int col = rem >> 5;
      int kk  = rem & 31;
      int t = ks*32 + kk;            // h*128 + k
      int h = t >> 7, k = t & 127;
      Bt2[i] = f2bf(gat_w[(size_t)k*384 + h*128 + col] * (1.f/3.f));
    }
  }
}

// ---- alloc: rowptr/cursor via wave prefix-scan + one block atomic ----
// Row order is arbitrary (block race) — correctness is order-independent.
__global__ __launch_bounds__(256)
void alloc_kernel(const int* __restrict__ deg, int* __restrict__ gcount,
                  int* __restrict__ rowptr, int* __restrict__ cursor, int nN)
{
  int tid = threadIdx.x, wave = tid>>6, lane = tid&63;
  int n = blockIdx.x*256 + tid;
  int v = (n < nN) ? deg[n]+1 : 0;   // +1 = self-loop slot
  int sc = v;
  #pragma unroll
  for (int off=1; off<64; off<<=1){
    int t = __shfl_up(sc, off);
    if (lane >= off) sc += t;
  }
  __shared__ int ws[4];
  __shared__ int bbase;
  if (lane==63) ws[wave] = sc;
  __syncthreads();
  if (tid==0) bbase = atomicAdd(gcount, ws[0]+ws[1]+ws[2]+ws[3]);
  __syncthreads();
  int wbase = 0;
  for (int i=0;i<wave;i++) wbase += ws[i];
  int excl = bbase + wbase + sc - v;
  if (n < nN){ rowptr[n] = excl; cursor[n] = excl; }
}

// ---- scatter: per-edge alpha -> val {p0,p1,p2,src}; self-loop slots last ----
__global__ __launch_bounds__(256)
void scatter_kernel(const int* __restrict__ ei, int* __restrict__ cursor,
                    const float* __restrict__ a_s, const float* __restrict__ a_d,
                    const int* __restrict__ rowptr, const int* __restrict__ deg,
                    float4* __restrict__ val, int nE, int ebN, int nN)
{
  if (blockIdx.x < (unsigned)ebN){
    int e = blockIdx.x*256 + threadIdx.x;
    if (e < nE){
      int s = ei[e], d = ei[nE + e];
      float e0 = a_s[(size_t)s*3+0] + a_d[(size_t)d*3+0]; e0 = e0>0.f ? e0 : NEG*e0;
      float e1 = a_s[(size_t)s*3+1] + a_d[(size_t)d*3+1]; e1 = e1>0.f ? e1 : NEG*e1;
      float e2 = a_s[(size_t)s*3+2] + a_d[(size_t)d*3+2]; e2 = e2>0.f ? e2 : NEG*e2;
      int pos = atomicAdd(&cursor[d], 1);
      val[pos] = make_float4(__expf(e0), __expf(e1), __expf(e2), __int_as_float(s));
    }
  } else {
    int n = (blockIdx.x - ebN)*256 + threadIdx.x;
    if (n < nN){
      float e0 = a_s[(size_t)n*3+0] + a_d[(size_t)n*3+0]; e0 = e0>0.f ? e0 : NEG*e0;
      float e1 = a_s[(size_t)n*3+1] + a_d[(size_t)n*3+1]; e1 = e1>0.f ? e1 : NEG*e1;
      float e2 = a_s[(size_t)n*3+2] + a_d[(size_t)n*3+2]; e2 = e2>0.f ? e2 : NEG*e2;
      val[rowptr[n] + deg[n]] = make_float4(__expf(e0), __expf(e1), __expf(e2),
                                            __int_as_float(n));
    }
  }
}

// ---- gathermm: phase1 gather->LDS (32 nodes), phase2 MFMA + epilogue ----
__global__ __launch_bounds__(256)
void gathermm_kernel(const int* __restrict__ rowptr, const int* __restrict__ deg,
                     const float4* __restrict__ val,
                     const unsigned short* __restrict__ h_bf,
                     const unsigned short* __restrict__ Bt2,
                     const float* __restrict__ gat_bias,
                     const float* __restrict__ out_w, const float* __restrict__ out_b,
                     float* __restrict__ out, int nN)
{
  __shared__ __align__(16) unsigned short hs[32][392];  // padded: 784B row stride
  int tid = threadIdx.x;
  int wave = tid >> 6, lane = tid & 63;
  int g = lane >> 4, lin = lane & 15;
  int nb0 = blockIdx.x*32;

  // ---- phase 1: gather (2 passes x 16 nodes), 16-lane group per node ----
  for (int pass=0; pass<2; ++pass){
    int local = pass*16 + wave*4 + g;
    int n = nb0 + local;
    int valid = (n < nN);
    int nc = valid ? n : 0;
    int ro   = rowptr[nc];
    int degT = valid ? (deg[nc] + 1) : 0;

    float a0[8], a1[8], a2[8];
    #pragma unroll
    for (int c=0;c<8;c++){ a0[c]=0.f; a1[c]=0.f; a2[c]=0.f; }
    float den0=0.f, den1=0.f, den2=0.f;

    const unsigned short* hb = h_bf + 8*lin;
    const float4* vrow = val + ro;

    int j = 0;
    for (; j+1 < degT; j += 2){
      float4 vA = vrow[j];
      float4 vB = vrow[j+1];
      int sA = __float_as_int(vA.w);
      int sB = __float_as_int(vB.w);
      ushort8 ha = *(const ushort8*)(hb + (size_t)sA*128);
      ushort8 hc = *(const ushort8*)(hb + (size_t)sB*128);
      den0 += vA.x + vB.x; den1 += vA.y + vB.y; den2 += vA.z + vB.z;
      #pragma unroll
      for (int c=0;c<8;c++){
        float fa = bf2f(ha[c]), fb = bf2f(hc[c]);
        a0[c] += vA.x*fa + vB.x*fb;
        a1[c] += vA.y*fa + vB.y*fb;
        a2[c] += vA.z*fa + vB.z*fb;
      }
    }
    if (j < degT){
      float4 vA = vrow[j];
      int sA = __float_as_int(vA.w);
      ushort8 ha = *(const ushort8*)(hb + (size_t)sA*128);
      den0 += vA.x; den1 += vA.y; den2 += vA.z;
      #pragma unroll
      for (int c=0;c<8;c++){
        float fa = bf2f(ha[c]);
        a0[c] += vA.x*fa; a1[c] += vA.y*fa; a2[c] += vA.z*fa;
      }
    }

    if (valid){
      float w0 = 1.f/(den0+1e-16f);
      float w1 = 1.f/(den1+1e-16f);
      float w2 = 1.f/(den2+1e-16f);
      unsigned short o0[8], o1[8], o2[8];
      #pragma unroll
      for (int c=0;c<8;c++){
        o0[c] = f2bf(a0[c]*w0);
        o1[c] = f2bf(a1[c]*w1);
        o2[c] = f2bf(a2[c]*w2);
      }
      unsigned short* hp = &hs[local][8*lin];
      *(int4*)(hp      ) = *(int4*)o0;
      *(int4*)(hp + 128) = *(int4*)o1;
      *(int4*)(hp + 256) = *(int4*)o2;
    }
  }
  __syncthreads();

  // ---- phase 2: waves 0,1 do 16 rows x 128 cols MFMA; waves 2,3 retire ----
  if (wave >= 2) return;
  int cl = lane & 15, kg = lane >> 4;
  int rlocal = wave*16 + cl;
  const unsigned short* aBase = &hs[rlocal][0];

  f32x4 acc[8];
  #pragma unroll
  for (int f=0;f<8;f++) acc[f] = (f32x4){0.f,0.f,0.f,0.f};

  #pragma unroll
  for (int ks=0; ks<12; ks++){
    bf16x8 a = *(const bf16x8*)(aBase + ks*32 + kg*8);
    #pragma unroll
    for (int f=0;f<8;f++){
      bf16x8 b = *(const bf16x8*)(Bt2 + (size_t)ks*4096 + (f*16 + cl)*32 + kg*8);
      acc[f] = __builtin_amdgcn_mfma_f32_16x16x32_bf16(a, b, acc[f], 0, 0, 0);
    }
  }

  float p[4][4];
  #pragma unroll
  for (int r=0;r<4;r++)
    #pragma unroll
    for (int j2=0;j2<4;j2++) p[r][j2]=0.f;

  int r0 = nb0 + wave*16;
  #pragma unroll
  for (int f=0;f<8;f++){
    int col = f*16 + cl;
    float bias = gat_bias[col];
    float w0=out_w[col*4+0], w1=out_w[col*4+1], w2=out_w[col*4+2], w3=out_w[col*4+3];
    #pragma unroll
    for (int r=0;r<4;r++){
      int row = r0 + kg*4 + r;
      float hres = (row < nN) ? bf2f(h_bf[(size_t)row*128 + col]) : 0.f;
      float xn = acc[f][r] + bias + hres;
      p[r][0] += xn*w0; p[r][1] += xn*w1; p[r][2] += xn*w2; p[r][3] += xn*w3;
    }
  }
  #pragma unroll
  for (int off=1; off<16; off<<=1){
    #pragma unroll
    for (int r=0;r<4;r++)
      #pragma unroll
      for (int j2=0;j2<4;j2++) p[r][j2] += __shfl_xor(p[r][j2], off);
  }
  if (cl == 0){
    #pragma unroll
    for (int r=0;r<4;r++){
      int row = r0 + kg*4 + r;
      if (row < nN){
        float4 o = {p[r][0]+out_b[0], p[r][1]+out_b[1], p[r][2]+out_b[2], p[r][3]+out_b[3]};
        *(float4*)(out + (size_t)row*4) = o;
      }
    }
  }
}

extern "C" void kernel_launch(void* const* d_in, const int* in_sizes, int n_in,
                              void* d_out, int out_size, void* d_ws, size_t ws_size,
                              hipStream_t stream) {
  const float* x       = (const float*)d_in[0];
  const float* emb_w   = (const float*)d_in[1];
  const float* emb_b   = (const float*)d_in[2];
  const float* gat_w   = (const float*)d_in[3];
  const float* att_src = (const float*)d_in[4];
  const float* att_dst = (const float*)d_in[5];
  const float* gat_bias= (const float*)d_in[6];
  const float* out_w   = (const float*)d_in[7];
  const float* out_b   = (const float*)d_in[8];
  const int*   ei      = (const int*)d_in[9];
  float* out = (float*)d_out;

  int nN = in_sizes[0]/9;
  int nE = in_sizes[9]/2;
  int nB = (nN + SBS - 1) / SBS;     // 196
  int ebN = (nE + 255)/256;

  char* p = (char*)d_ws;
  auto alloc = [&](size_t bytes)->char*{
    char* r = p; p += (bytes + 255) & ~(size_t)255; return r;
  };
  unsigned short* h_bf   = (unsigned short*)alloc((size_t)nN*128*2);
  float*          a_s    = (float*)         alloc((size_t)nN*3*4);
  float*          a_d    = (float*)         alloc((size_t)nN*3*4);
  unsigned short* Bt2    = (unsigned short*)alloc((size_t)12*128*32*2);
  int*            deg    = (int*)           alloc((size_t)nN*4);
  int*            rowptr = (int*)           alloc((size_t)nN*4);
  int*            cursor = (int*)           alloc((size_t)nN*4);
  int*            gcount = (int*)           alloc(256);
  float4*         val    = (float4*)        alloc(((size_t)nE+nN)*16);

  // 1: embed (+ zero deg/gcount)
  embed_kernel<<<nB, 256, 0, stream>>>(
      x, emb_w, emb_b, gat_w, att_src, att_dst, h_bf, a_s, a_d, deg, gcount, nN);

  // 2: histogram + Bt2
  deg_kernel<<<ebN + 192, 256, 0, stream>>>(ei, deg, gat_w, Bt2, nE, ebN);

  // 3: row allocation (wave-scan + per-block atomic)
  alloc_kernel<<<nB, 256, 0, stream>>>(deg, gcount, rowptr, cursor, nN);

  // 4: alpha precompute scatter (+ self-loop slots)
  scatter_kernel<<<ebN + nB, 256, 0, stream>>>(
      ei, cursor, a_s, a_d, rowptr, deg, val, nE, ebN, nN);

  // 5: fused gather + projection GEMM + epilogue
  gathermm_kernel<<<(nN+31)/32, 256, 0, stream>>>(
      rowptr, deg, val, h_bf, Bt2, gat_bias, out_w, out_b, out, nN);
}

// Round 15
// 206.208 us; speedup vs baseline: 1.0320x; 1.0320x over previous
//
#include <hip/hip_runtime.h>
#include <hip/hip_bf16.h>
#include <cstdint>

#define NEG 0.2f
#define SBS 256
#define PADK 56        // LDS col stride (ushorts): 112B, 16B-aligned, conflict-free

typedef __attribute__((ext_vector_type(8))) short bf16x8;
typedef __attribute__((ext_vector_type(8))) unsigned short ushort8;
typedef __attribute__((ext_vector_type(4))) float f32x4;

__device__ __forceinline__ float bf2f(unsigned short u){
  return __uint_as_float(((unsigned)u)<<16);
}
__device__ __forceinline__ unsigned short f2bf(float f){
  __hip_bfloat16 b = __float2bfloat16(f);   // RNE
  return *reinterpret_cast<unsigned short*>(&b);
}

// ---- embed: w_att in LDS, thread-per-node h/a_s/a_d; zeroes deg + gcount ----
__global__ __launch_bounds__(256)
void embed_kernel(const float* __restrict__ x, const float* __restrict__ emb_w,
                  const float* __restrict__ emb_b, const float* __restrict__ gat_w,
                  const float* __restrict__ att_src, const float* __restrict__ att_dst,
                  unsigned short* __restrict__ h_bf, float* __restrict__ a_s,
                  float* __restrict__ a_d, int* __restrict__ deg,
                  int* __restrict__ gcount, int nN)
{
  __shared__ float watt[768];     // [0:384)=src (h*128+k), [384:768)=dst
  int tid = threadIdx.x;

  #pragma unroll
  for (int r=0;r<3;r++){
    int o = tid + r*256;          // 0..767
    int isD = (o >= 384);
    int t2 = isD ? (o-384) : o;
    int h = t2 >> 7, k = t2 & 127;
    const float* att = isD ? (att_dst + h*128) : (att_src + h*128);
    const float* gw  = gat_w + (size_t)k*384 + h*128;
    float dot = 0.f;
    #pragma unroll 8
    for (int c=0;c<128;c++) dot += gw[c]*att[c];
    watt[o] = dot;
  }
  __syncthreads();

  int n = blockIdx.x*256 + tid;
  if (n < nN) deg[n] = 0;
  if (blockIdx.x==0 && tid==0) gcount[0] = 0;
  if (n >= nN) return;

  float xv[9];
  #pragma unroll
  for (int k=0;k<9;k++) xv[k] = x[(size_t)n*9 + k];

  float s0=0.f,s1=0.f,s2=0.f, d0=0.f,d1=0.f,d2=0.f;
  unsigned short* hrow = h_bf + (size_t)n*128;

  #pragma unroll 4
  for (int c0=0; c0<128; c0+=8){
    unsigned short pk[8];
    #pragma unroll
    for (int j=0;j<8;j++){
      int c = c0 + j;
      float acc = emb_b[c];
      #pragma unroll
      for (int k=0;k<9;k++) acc += xv[k]*emb_w[k*128+c];
      pk[j] = f2bf(acc);
      s0 += acc*watt[c]; s1 += acc*watt[128+c]; s2 += acc*watt[256+c];
      d0 += acc*watt[384+c]; d1 += acc*watt[512+c]; d2 += acc*watt[640+c];
    }
    *(int4*)(hrow + c0) = *(int4*)pk;
  }
  a_s[(size_t)n*3+0]=s0; a_s[(size_t)n*3+1]=s1; a_s[(size_t)n*3+2]=s2;
  a_d[(size_t)n*3+0]=d0; a_d[(size_t)n*3+1]=d1; a_d[(size_t)n*3+2]=d2;
}

// ---- deg histogram (scattered atomics over 50K counters); extra blocks Bt2 ----
__global__ __launch_bounds__(256)
void deg_kernel(const int* __restrict__ ei, int* __restrict__ deg,
                const float* __restrict__ gat_w,
                unsigned short* __restrict__ Bt2, int nE, int ebN)
{
  if (blockIdx.x < (unsigned)ebN){
    int e = blockIdx.x*256 + threadIdx.x;
    if (e < nE) atomicAdd(&deg[ei[nE + e]], 1);
  } else {
    int i = (blockIdx.x - ebN)*256 + threadIdx.x;   // 0..49151
    if (i < 12*128*32){
      int ks  = i >> 12;
      int rem = i & 4095;
      int col = rem >> 5;
      int kk  = rem & 31;
      int t = ks*32 + kk;            // h*128 + k
      int h = t >> 7, k = t & 127;
      Bt2[i] = f2bf(gat_w[(size_t)k*384 + h*128 + col] * (1.f/3.f));
    }
  }
}

// ---- alloc: rowptr/cursor via wave prefix-scan + one pre-aggregated atomic ----
// Row placement order is arbitrary (block race) — all consumers use rowptr/deg,
// never adjacency of rows, so correctness is order-independent.
__global__ __launch_bounds__(256)
void alloc_kernel(const int* __restrict__ deg, int* __restrict__ gcount,
                  int* __restrict__ rowptr, int* __restrict__ cursor, int nN)
{
  int tid = threadIdx.x, wave = tid>>6, lane = tid&63;
  int n = blockIdx.x*256 + tid;
  int v = (n < nN) ? deg[n]+1 : 0;   // +1 = self-loop slot
  int sc = v;
  #pragma unroll
  for (int off=1; off<64; off<<=1){
    int t = __shfl_up(sc, off);
    if (lane >= off) sc += t;
  }
  __shared__ int ws[4];
  __shared__ int bbase;
  if (lane==63) ws[wave] = sc;
  __syncthreads();
  if (tid==0) bbase = atomicAdd(gcount, ws[0]+ws[1]+ws[2]+ws[3]);
  __syncthreads();
  int wbase = 0;
  for (int i=0;i<wave;i++) wbase += ws[i];
  int excl = bbase + wbase + sc - v;
  if (n < nN){ rowptr[n] = excl; cursor[n] = excl; }
}

// ---- scatter: per-edge alpha -> val {p0,p1,p2,src}; self-loop slot last ----
__global__ __launch_bounds__(256)
void scatter_kernel(const int* __restrict__ ei, int* __restrict__ cursor,
                    const float* __restrict__ a_s, const float* __restrict__ a_d,
                    const int* __restrict__ rowptr, const int* __restrict__ deg,
                    float4* __restrict__ val, int nE, int ebN, int nN)
{
  if (blockIdx.x < (unsigned)ebN){
    int e = blockIdx.x*256 + threadIdx.x;
    if (e < nE){
      int s = ei[e], d = ei[nE + e];
      float e0 = a_s[(size_t)s*3+0] + a_d[(size_t)d*3+0]; e0 = e0>0.f ? e0 : NEG*e0;
      float e1 = a_s[(size_t)s*3+1] + a_d[(size_t)d*3+1]; e1 = e1>0.f ? e1 : NEG*e1;
      float e2 = a_s[(size_t)s*3+2] + a_d[(size_t)d*3+2]; e2 = e2>0.f ? e2 : NEG*e2;
      int pos = atomicAdd(&cursor[d], 1);
      val[pos] = make_float4(__expf(e0), __expf(e1), __expf(e2), __int_as_float(s));
    }
  } else {
    int n = (blockIdx.x - ebN)*256 + threadIdx.x;
    if (n < nN){
      float e0 = a_s[(size_t)n*3+0] + a_d[(size_t)n*3+0]; e0 = e0>0.f ? e0 : NEG*e0;
      float e1 = a_s[(size_t)n*3+1] + a_d[(size_t)n*3+1]; e1 = e1>0.f ? e1 : NEG*e1;
      float e2 = a_s[(size_t)n*3+2] + a_d[(size_t)n*3+2]; e2 = e2>0.f ? e2 : NEG*e2;
      val[rowptr[n] + deg[n]] = make_float4(__expf(e0), __expf(e1), __expf(e2),
                                            __int_as_float(n));
    }
  }
}

// ---- gather v5: 4 nodes/wave (16-lane groups), shuffle-free, exp-free ----
__global__ __launch_bounds__(256)
void gather_kernel(const int* __restrict__ rowptr, const int* __restrict__ deg,
                   const float4* __restrict__ val,
                   const unsigned short* __restrict__ h_bf,
                   unsigned short* __restrict__ hagg, int nN)
{
  int wave = threadIdx.x >> 6, lane = threadIdx.x & 63;
  int g   = lane >> 4;          // group within wave (0..3)
  int lin = lane & 15;          // lane within group -> 8 channels
  int n = blockIdx.x*16 + wave*4 + g;
  int valid = (n < nN);
  int nc = valid ? n : (nN-1);

  int ro   = rowptr[nc];
  int degT = valid ? (deg[nc] + 1) : 0;   // includes self-loop slot

  float a0[8], a1[8], a2[8];
  #pragma unroll
  for (int c=0;c<8;c++){ a0[c]=0.f; a1[c]=0.f; a2[c]=0.f; }
  float den0=0.f, den1=0.f, den2=0.f;

  const unsigned short* hb = h_bf + 8*lin;
  const float4* vrow = val + ro;

  int j = 0;
  for (; j+1 < degT; j += 2){
    float4 vA = vrow[j];
    float4 vB = vrow[j+1];
    int sA = __float_as_int(vA.w);
    int sB = __float_as_int(vB.w);
    ushort8 ha = *(const ushort8*)(hb + (size_t)sA*128);
    ushort8 hc = *(const ushort8*)(hb + (size_t)sB*128);
    den0 += vA.x + vB.x; den1 += vA.y + vB.y; den2 += vA.z + vB.z;
    #pragma unroll
    for (int c=0;c<8;c++){
      float fa = bf2f(ha[c]), fb = bf2f(hc[c]);
      a0[c] += vA.x*fa + vB.x*fb;
      a1[c] += vA.y*fa + vB.y*fb;
      a2[c] += vA.z*fa + vB.z*fb;
    }
  }
  if (j < degT){
    float4 vA = vrow[j];
    int sA = __float_as_int(vA.w);
    ushort8 ha = *(const ushort8*)(hb + (size_t)sA*128);
    den0 += vA.x; den1 += vA.y; den2 += vA.z;
    #pragma unroll
    for (int c=0;c<8;c++){
      float fa = bf2f(ha[c]);
      a0[c] += vA.x*fa; a1[c] += vA.y*fa; a2[c] += vA.z*fa;
    }
  }

  if (valid){
    float w0 = 1.f/(den0+1e-16f);
    float w1 = 1.f/(den1+1e-16f);
    float w2 = 1.f/(den2+1e-16f);
    unsigned short o0[8], o1[8], o2[8];
    #pragma unroll
    for (int c=0;c<8;c++){
      o0[c] = f2bf(a0[c]*w0);
      o1[c] = f2bf(a1[c]*w1);
      o2[c] = f2bf(a2[c]*w2);
    }
    size_t bi = (size_t)n*384 + 8*lin;
    *(int4*)(hagg + bi      ) = *(int4*)o0;
    *(int4*)(hagg + bi + 128) = *(int4*)o1;
    *(int4*)(hagg + bi + 256) = *(int4*)o2;
  }
}

// ---- gemm2: LDS-staged B, double-buffered, software-pipelined ----
__global__ __launch_bounds__(256)
void gemm2_kernel(const unsigned short* __restrict__ hagg,
                  const unsigned short* __restrict__ Bt2,
                  const unsigned short* __restrict__ h_bf,
                  const float* __restrict__ gat_bias,
                  const float* __restrict__ out_w, const float* __restrict__ out_b,
                  float* __restrict__ out, int nN)
{
  __shared__ __align__(16) unsigned short Bs[2][128*PADK];
  int tid  = threadIdx.x;
  int wave = tid >> 6, lane = tid & 63;
  int cl = lane & 15, kg = lane >> 4;
  int r0 = blockIdx.x*64 + wave*16;
  int rowA = min(r0 + cl, nN-1);
  const unsigned short* aBase = hagg + (size_t)rowA*384 + kg*8;

  int scol = tid >> 1, shalf = tid & 1;
  int dstI = scol*(PADK/8) + shalf*2;

  {
    const int4* src = (const int4*)Bt2;
    int4 t0 = src[2*tid], t1 = src[2*tid+1];
    ((int4*)Bs[0])[dstI]   = t0;
    ((int4*)Bs[0])[dstI+1] = t1;
  }
  f32x4 acc[8];
  #pragma unroll
  for (int f=0;f<8;f++) acc[f] = (f32x4){0.f,0.f,0.f,0.f};
  bf16x8 aCur = *(const bf16x8*)(aBase);
  __syncthreads();

  #pragma unroll
  for (int ks=0; ks<12; ks++){
    int4 t0, t1; bf16x8 aNext;
    if (ks < 11){
      const int4* src = (const int4*)(Bt2 + (size_t)(ks+1)*4096);
      t0 = src[2*tid]; t1 = src[2*tid+1];
      aNext = *(const bf16x8*)(aBase + (ks+1)*32);
    }
    const unsigned short* bs = Bs[ks & 1];
    #pragma unroll
    for (int f=0;f<8;f++){
      bf16x8 b = *(const bf16x8*)(bs + (f*16 + cl)*PADK + kg*8);
      acc[f] = __builtin_amdgcn_mfma_f32_16x16x32_bf16(aCur, b, acc[f], 0, 0, 0);
    }
    if (ks < 11){
      int4* dst = (int4*)Bs[(ks+1) & 1];
      dst[dstI]   = t0;
      dst[dstI+1] = t1;
      aCur = aNext;
    }
    __syncthreads();
  }

  float p[4][4];
  #pragma unroll
  for (int r=0;r<4;r++)
    #pragma unroll
    for (int j=0;j<4;j++) p[r][j]=0.f;

  #pragma unroll
  for (int f=0;f<8;f++){
    int col = f*16 + cl;
    float bias = gat_bias[col];
    float w0=out_w[col*4+0], w1=out_w[col*4+1], w2=out_w[col*4+2], w3=out_w[col*4+3];
    #pragma unroll
    for (int r=0;r<4;r++){
      int row = r0 + kg*4 + r;
      float hres = (row < nN) ? bf2f(h_bf[(size_t)row*128 + col]) : 0.f;
      float xn = acc[f][r] + bias + hres;
      p[r][0] += xn*w0; p[r][1] += xn*w1; p[r][2] += xn*w2; p[r][3] += xn*w3;
    }
  }
  #pragma unroll
  for (int off=1; off<16; off<<=1){
    #pragma unroll
    for (int r=0;r<4;r++)
      #pragma unroll
      for (int j=0;j<4;j++) p[r][j] += __shfl_xor(p[r][j], off);
  }
  if (cl == 0){
    #pragma unroll
    for (int r=0;r<4;r++){
      int row = r0 + kg*4 + r;
      if (row < nN){
        float4 o = {p[r][0]+out_b[0], p[r][1]+out_b[1], p[r][2]+out_b[2], p[r][3]+out_b[3]};
        *(float4*)(out + (size_t)row*4) = o;
      }
    }
  }
}

extern "C" void kernel_launch(void* const* d_in, const int* in_sizes, int n_in,
                              void* d_out, int out_size, void* d_ws, size_t ws_size,
                              hipStream_t stream) {
  const float* x       = (const float*)d_in[0];
  const float* emb_w   = (const float*)d_in[1];
  const float* emb_b   = (const float*)d_in[2];
  const float* gat_w   = (const float*)d_in[3];
  const float* att_src = (const float*)d_in[4];
  const float* att_dst = (const float*)d_in[5];
  const float* gat_bias= (const float*)d_in[6];
  const float* out_w   = (const float*)d_in[7];
  const float* out_b   = (const float*)d_in[8];
  const int*   ei      = (const int*)d_in[9];
  float* out = (float*)d_out;

  int nN = in_sizes[0]/9;
  int nE = in_sizes[9]/2;
  int nB = (nN + SBS - 1) / SBS;     // 196
  int ebN = (nE + 255)/256;

  char* p = (char*)d_ws;
  auto alloc = [&](size_t bytes)->char*{
    char* r = p; p += (bytes + 255) & ~(size_t)255; return r;
  };
  unsigned short* h_bf   = (unsigned short*)alloc((size_t)nN*128*2);
  float*          a_s    = (float*)         alloc((size_t)nN*3*4);
  float*          a_d    = (float*)         alloc((size_t)nN*3*4);
  unsigned short* Bt2    = (unsigned short*)alloc((size_t)12*128*32*2);
  int*            deg    = (int*)           alloc((size_t)nN*4);
  int*            rowptr = (int*)           alloc((size_t)nN*4);
  int*            cursor = (int*)           alloc((size_t)nN*4);
  int*            gcount = (int*)           alloc(256);
  float4*         val    = (float4*)        alloc(((size_t)nE+nN)*16);
  unsigned short* hagg   = (unsigned short*)alloc((size_t)nN*384*2);

  // 1: embed (+ zero deg/gcount)
  embed_kernel<<<nB, 256, 0, stream>>>(
      x, emb_w, emb_b, gat_w, att_src, att_dst, h_bf, a_s, a_d, deg, gcount, nN);

  // 2: histogram + Bt2
  deg_kernel<<<ebN + 192, 256, 0, stream>>>(ei, deg, gat_w, Bt2, nE, ebN);

  // 3: row allocation (wave-scan + per-block pre-aggregated atomic)
  alloc_kernel<<<nB, 256, 0, stream>>>(deg, gcount, rowptr, cursor, nN);

  // 4: alpha precompute scatter (+ self-loop slots)
  scatter_kernel<<<ebN + nB, 256, 0, stream>>>(
      ei, cursor, a_s, a_d, rowptr, deg, val, nE, ebN, nN);

  // 5: gather (unfused — latency-bound phase keeps full occupancy)
  gather_kernel<<<(nN+15)/16, 256, 0, stream>>>(
      rowptr, deg, val, h_bf, hagg, nN);

  // 6: projection GEMM + epilogue
  gemm2_kernel<<<(nN+63)/64, 256, 0, stream>>>(
      hagg, Bt2, h_bf, gat_bias, out_w, out_b, out, nN);
}